// Round 5
// baseline (207.878 us; speedup 1.0000x reference)
//
#include <hip/hip_runtime.h>
#include <cstdint>
#include <cstddef>

#define B_ 8
#define C_ 10
#define HW_ 65536
#define NPIX_ (B_ * HW_)
#define NB_ 2048   // 2048 blocks * 256 threads = 524288 = exactly 1 px/thread

__device__ __forceinline__ float sl1f(float p, float t) {
    float d = fabsf(p - t);
    return (d < 1.0f) ? 0.5f * d * d : d - 0.5f;
}

__global__ __launch_bounds__(256) void bev_loss_main(
    const float* __restrict__ cls_pred, const float* __restrict__ reg_pred,
    const float* __restrict__ iou_pred, const int* __restrict__ cls_tg,
    const float* __restrict__ reg_tg, const float* __restrict__ reg_w,
    const float* __restrict__ iou_tg, double* __restrict__ part,
    unsigned int* __restrict__ ticket, float* __restrict__ out)
{
    int n  = blockIdx.x * blockDim.x + threadIdx.x;   // 0 .. NPIX_-1
    int b  = n >> 16;
    int hw = n & 65535;

    // ---------------- coalesced scalar loads (stride-1 across lanes) ----------
    float lg[C_];
    {
        const float* cp = cls_pred + (size_t)b * C_ * HW_ + hw;
        #pragma unroll
        for (int c = 0; c < C_; c++) lg[c] = cp[(size_t)c * HW_];
    }
    float P[9], T[9];
    {
        const float* rp = reg_pred + (size_t)b * 9 * HW_ + hw;
        const float* rt = reg_tg  + (size_t)b * 9 * HW_ + hw;
        #pragma unroll
        for (int k = 0; k < 9; k++) { P[k] = rp[(size_t)k * HW_]; T[k] = rt[(size_t)k * HW_]; }
    }
    int   ct = cls_tg[n];
    float w  = reg_w[n];
    float xi = iou_pred[n];
    float yi = iou_tg[n];

    // ---------------- classification focal loss ----------------
    float o0;
    {
        float m = lg[0];
        #pragma unroll
        for (int c = 1; c < C_; c++) m = fmaxf(m, lg[c]);
        int tl = ct < 0 ? 0 : (ct > C_ - 1 ? C_ - 1 : ct);
        float se = 0.f, et = 0.f;
        #pragma unroll
        for (int c = 0; c < C_; c++) {
            float e = __expf(lg[c] - m);
            se += e;
            et = (c == tl) ? e : et;
        }
        float pt = __fdividef(et, se);
        pt = fminf(fmaxf(pt, 1e-7f), 1.0f - 1e-7f);
        float alpha_t = (ct > 0) ? 0.25f : 0.75f;
        float omp = 1.0f - pt;
        float fl = -alpha_t * omp * omp * __logf(pt);
        o0 = (ct >= 0) ? fl : 0.0f;
    }

    float pos = (w > 0.f) ? 1.f : 0.f;

    // ---------------- corners ----------------
    float Ax[4], Ay[4], Bx[4], By[4];
    {
        const float sbx[4] = { 1.f, -1.f, -1.f, 1.f };
        const float sby[4] = { -1.f, -1.f, 1.f, 1.f };
        float hx = 0.5f * P[3], hy = 0.5f * P[4];
        float ss, cc; __sincosf(P[6], &ss, &cc);
        #pragma unroll
        for (int i = 0; i < 4; i++) {
            float px = sbx[i] * hx, py = sby[i] * hy;
            Ax[i] = px * cc - py * ss + P[0];
            Ay[i] = px * ss + py * cc + P[1];
        }
        float hx2 = 0.5f * T[3], hy2 = 0.5f * T[4];
        float ss2, cc2; __sincosf(T[6], &ss2, &cc2);
        #pragma unroll
        for (int i = 0; i < 4; i++) {
            float px = sbx[i] * hx2, py = sby[i] * hy2;
            Bx[i] = px * cc2 - py * ss2 + T[0];
            By[i] = px * ss2 + py * cc2 + T[1];
        }
    }

    // ---------------- signed areas + orientation signs ----------------
    float sa = 0.f, sb = 0.f;
    #pragma unroll
    for (int i = 0; i < 4; i++) {
        int j = (i + 1) & 3;
        sa += Ax[i] * Ay[j] - Ay[i] * Ax[j];
        sb += Bx[i] * By[j] - By[i] * Bx[j];
    }
    sa *= 0.5f; sb *= 0.5f;
    float sgnA = (sa > 0.f) ? 1.f : ((sa < 0.f) ? -1.f : 0.f);
    float sgnB = (sb > 0.f) ? 1.f : ((sb < 0.f) ? -1.f : 0.f);

    // ---------------- rotated IoU: Green's-theorem clip, fully branchless ----
    float S = 0.f;
    {
        float dB[4][4];
        #pragma unroll
        for (int j = 0; j < 4; j++) {
            int j1 = (j + 1) & 3;
            float sx = sgnB * (Bx[j1] - Bx[j]);
            float sy = sgnB * (By[j1] - By[j]);
            float kj = sx * By[j] - sy * Bx[j];
            #pragma unroll
            for (int i = 0; i < 4; i++)
                dB[j][i] = sx * Ay[i] - sy * Ax[i] - kj;
        }
        #pragma unroll
        for (int i = 0; i < 4; i++) {
            int i1 = (i + 1) & 3;
            float t0 = 0.f, t1 = 1.f;
            #pragma unroll
            for (int j = 0; j < 4; j++) {
                float d0 = dB[j][i], d1 = dB[j][i1];
                float den = d1 - d0;
                float t = __fdividef(-d0, den);
                float lo = (den > 0.f) ? t : ((den == 0.f && d0 < 0.f) ? 2.f : 0.f);
                float hi = (den < 0.f) ? t : 1.f;
                t0 = fmaxf(t0, lo);
                t1 = fminf(t1, hi);
            }
            S += (Ax[i] * Ay[i1] - Ay[i] * Ax[i1]) * fmaxf(t1 - t0, 0.f);
        }
    }
    {
        float dA[4][4];
        #pragma unroll
        for (int j = 0; j < 4; j++) {
            int j1 = (j + 1) & 3;
            float sx = sgnA * (Ax[j1] - Ax[j]);
            float sy = sgnA * (Ay[j1] - Ay[j]);
            float kj = sx * Ay[j] - sy * Ax[j];
            #pragma unroll
            for (int i = 0; i < 4; i++)
                dA[j][i] = sx * By[i] - sy * Bx[i] - kj;
        }
        #pragma unroll
        for (int i = 0; i < 4; i++) {
            int i1 = (i + 1) & 3;
            float t0 = 0.f, t1 = 1.f;
            #pragma unroll
            for (int j = 0; j < 4; j++) {
                float d0 = dA[j][i], d1 = dA[j][i1];
                float den = d1 - d0;
                float t = __fdividef(-d0, den);
                float lo = (den > 0.f) ? t : ((den == 0.f && d0 < 0.f) ? 2.f : 0.f);
                float hi = (den < 0.f) ? t : 1.f;
                t0 = fmaxf(t0, lo);
                t1 = fminf(t1, hi);
            }
            S += (Bx[i] * By[i1] - By[i] * Bx[i1]) * fmaxf(t1 - t0, 0.f);
        }
    }
    float inter = 0.5f * fabsf(S);
    float areaA = fabsf(sa), areaB = fabsf(sb);
    float uni = areaA + areaB - inter;
    float iou = (uni > 1e-7f) ? __fdividef(inter, uni) : 0.f;

    // ---------------- DIoU-style bev loss ----------------
    float o1;
    {
        float ddx = P[0] - T[0], ddy = P[1] - T[1];
        float d2 = fmaf(ddx, ddx, ddy * ddy);
        float mnx = Ax[0], mxx = Ax[0], mny = Ay[0], mxy = Ay[0];
        #pragma unroll
        for (int i = 1; i < 4; i++) {
            mnx = fminf(mnx, Ax[i]); mxx = fmaxf(mxx, Ax[i]);
            mny = fminf(mny, Ay[i]); mxy = fmaxf(mxy, Ay[i]);
        }
        #pragma unroll
        for (int i = 0; i < 4; i++) {
            mnx = fminf(mnx, Bx[i]); mxx = fmaxf(mxx, Bx[i]);
            mny = fminf(mny, By[i]); mxy = fmaxf(mxy, By[i]);
        }
        float exd = mxx - mnx, eyd = mxy - mny;
        float c2 = fmaxf(fmaf(exd, exd, eyd * eyd), 1e-7f);

        // atan(rp) - atan(rt) = atan((rp-rt)/(1+rp*rt))  (rp,rt >= 0 here)
        float rp = __fdividef(P[4], fmaxf(P[3], 1e-7f));
        float rt = __fdividef(T[4], fmaxf(T[3], 1e-7f));
        float dv = atanf(__fdividef(rp - rt, fmaf(rp, rt, 1.f)));
        float v = 0.4052847345693511f * dv * dv;
        float alpha_c = __fdividef(v, 1.0f - iou + v + 1e-7f);
        float lbev = 1.0f - iou + __fdividef(d2, c2) + alpha_c * v;
        o1 = lbev * pos;
    }

    // ---------------- smooth-L1 z / h / vel + BCE ----------------
    float o2 = sl1f(P[2], T[2]) * pos;
    float o3 = sl1f(P[5], T[5]) * pos;
    float o4 = (sl1f(P[7], T[7]) + sl1f(P[8], T[8])) * pos;
    float bce = fmaxf(xi, 0.f) - xi * yi + __logf(1.0f + __expf(-fabsf(xi)));
    float o5 = bce * pos;

    // ---------------- block reduction ----------------
    double a[7] = { (double)o0, (double)o1, (double)o2, (double)o3,
                    (double)o4, (double)o5, (double)pos };
    __shared__ double red[7][4];
    __shared__ bool lastf;
    int lane = threadIdx.x & 63;
    int wv   = threadIdx.x >> 6;
    #pragma unroll
    for (int k = 0; k < 7; k++) {
        double s = a[k];
        for (int off = 32; off > 0; off >>= 1) s += __shfl_down(s, off, 64);
        if (lane == 0) red[k][wv] = s;
    }
    __syncthreads();
    if (threadIdx.x == 0) {
        #pragma unroll
        for (int k = 0; k < 7; k++)
            part[(size_t)k * NB_ + blockIdx.x] = red[k][0] + red[k][1] + red[k][2] + red[k][3];
    }
    __threadfence();                       // release partials (device scope)
    if (threadIdx.x == 0) {
        unsigned tk = atomicAdd(ticket, 1u);
        lastf = (tk == NB_ - 1);
    }
    __syncthreads();
    if (!lastf) return;

    // ---------------- final reduction in last-arriving block ----------------
    __threadfence();                       // acquire partials
    double s[7] = { 0, 0, 0, 0, 0, 0, 0 };
    #pragma unroll
    for (int k = 0; k < 7; k++)
        for (int r = threadIdx.x; r < NB_; r += 256)
            s[k] += part[(size_t)k * NB_ + r];
    #pragma unroll
    for (int k = 0; k < 7; k++) {
        double v = s[k];
        for (int off = 32; off > 0; off >>= 1) v += __shfl_down(v, off, 64);
        if (lane == 0) red[k][wv] = v;
    }
    __syncthreads();
    if (threadIdx.x == 0) {
        double npos = fmax(red[6][0] + red[6][1] + red[6][2] + red[6][3], 1.0);
        #pragma unroll
        for (int k = 0; k < 6; k++)
            out[k] = (float)((red[k][0] + red[k][1] + red[k][2] + red[k][3]) / npos);
    }
}

extern "C" void kernel_launch(void* const* d_in, const int* in_sizes, int n_in,
                              void* d_out, int out_size, void* d_ws, size_t ws_size,
                              hipStream_t stream) {
    const float* cls_pred = (const float*)d_in[0];
    const float* reg_pred = (const float*)d_in[1];
    const float* iou_pred = (const float*)d_in[2];
    const int*   cls_tg   = (const int*)d_in[3];
    const float* reg_tg   = (const float*)d_in[4];
    const float* reg_w    = (const float*)d_in[5];
    const float* iou_tg   = (const float*)d_in[6];
    float* out = (float*)d_out;

    double* part = (double*)d_ws;                              // 7 * NB_ doubles
    unsigned int* ticket = (unsigned int*)((char*)d_ws + (size_t)7 * NB_ * sizeof(double));

    hipMemsetAsync(ticket, 0, sizeof(unsigned int), stream);   // zero ticket each call

    bev_loss_main<<<NB_, 256, 0, stream>>>(cls_pred, reg_pred, iou_pred, cls_tg,
                                           reg_tg, reg_w, iou_tg, part, ticket, out);
}

// Round 6
// 35.457 us; speedup vs baseline: 5.8628x; 5.8628x over previous
//
#include <hip/hip_runtime.h>
#include <cstdint>
#include <cstddef>

#define B_ 8
#define C_ 10
#define HW_ 65536
#define NPIX_ (B_ * HW_)
#define NB_ 1024   // 1024 blocks * 256 threads * 2 px = 524288

__device__ __forceinline__ float sl1f(float p, float t) {
    float d = fabsf(p - t);
    return (d < 1.0f) ? 0.5f * d * d : d - 0.5f;
}
__device__ __forceinline__ void pinf(float v)  { asm volatile("" :: "v"(v)); }
__device__ __forceinline__ void pini(int v)    { asm volatile("" :: "v"(v)); }

// Full per-pixel loss: writes the 7 accumulator terms.
__device__ __forceinline__ void pixel_loss(
    const float lg[C_], int ct, const float P[9], const float T[9],
    float w, float xiou, float yiou, float o[7])
{
    // ---------------- classification focal loss ----------------
    float m = lg[0];
    #pragma unroll
    for (int c = 1; c < C_; c++) m = fmaxf(m, lg[c]);
    int tl = ct < 0 ? 0 : (ct > C_ - 1 ? C_ - 1 : ct);
    float se = 0.f, et = 0.f;
    #pragma unroll
    for (int c = 0; c < C_; c++) {
        float e = __expf(lg[c] - m);
        se += e;
        et = (c == tl) ? e : et;
    }
    float pt = __fdividef(et, se);
    pt = fminf(fmaxf(pt, 1e-7f), 1.0f - 1e-7f);
    float alpha_t = (ct > 0) ? 0.25f : 0.75f;
    float omp = 1.0f - pt;
    float fl = -alpha_t * omp * omp * __logf(pt);
    o[0] = (ct >= 0) ? fl : 0.0f;

    float pos = (w > 0.f) ? 1.f : 0.f;

    // ---------------- corners ----------------
    float Ax[4], Ay[4], Bx[4], By[4];
    {
        const float sbx[4] = { 1.f, -1.f, -1.f, 1.f };
        const float sby[4] = { -1.f, -1.f, 1.f, 1.f };
        float hx = 0.5f * P[3], hy = 0.5f * P[4];
        float ss, cc; __sincosf(P[6], &ss, &cc);
        #pragma unroll
        for (int i = 0; i < 4; i++) {
            float px = sbx[i] * hx, py = sby[i] * hy;
            Ax[i] = px * cc - py * ss + P[0];
            Ay[i] = px * ss + py * cc + P[1];
        }
        float hx2 = 0.5f * T[3], hy2 = 0.5f * T[4];
        float ss2, cc2; __sincosf(T[6], &ss2, &cc2);
        #pragma unroll
        for (int i = 0; i < 4; i++) {
            float px = sbx[i] * hx2, py = sby[i] * hy2;
            Bx[i] = px * cc2 - py * ss2 + T[0];
            By[i] = px * ss2 + py * cc2 + T[1];
        }
    }

    // ---------------- signed areas + orientation signs ----------------
    float sa = 0.f, sb = 0.f;
    #pragma unroll
    for (int i = 0; i < 4; i++) {
        int j = (i + 1) & 3;
        sa += Ax[i] * Ay[j] - Ay[i] * Ax[j];
        sb += Bx[i] * By[j] - By[i] * Bx[j];
    }
    sa *= 0.5f; sb *= 0.5f;
    float sgnA = (sa > 0.f) ? 1.f : ((sa < 0.f) ? -1.f : 0.f);
    float sgnB = (sb > 0.f) ? 1.f : ((sb < 0.f) ? -1.f : 0.f);

    // ---------------- rotated IoU: Green's-theorem clip, branchless ----------
    float S = 0.f;
    {
        float dB[4][4];
        #pragma unroll
        for (int j = 0; j < 4; j++) {
            int j1 = (j + 1) & 3;
            float sx = sgnB * (Bx[j1] - Bx[j]);
            float sy = sgnB * (By[j1] - By[j]);
            float kj = sx * By[j] - sy * Bx[j];
            #pragma unroll
            for (int i = 0; i < 4; i++)
                dB[j][i] = sx * Ay[i] - sy * Ax[i] - kj;
        }
        #pragma unroll
        for (int i = 0; i < 4; i++) {
            int i1 = (i + 1) & 3;
            float t0 = 0.f, t1 = 1.f;
            #pragma unroll
            for (int j = 0; j < 4; j++) {
                float d0 = dB[j][i], d1 = dB[j][i1];
                float den = d1 - d0;
                float t = __fdividef(-d0, den);
                float lo = (den > 0.f) ? t : ((den == 0.f && d0 < 0.f) ? 2.f : 0.f);
                float hi = (den < 0.f) ? t : 1.f;
                t0 = fmaxf(t0, lo);
                t1 = fminf(t1, hi);
            }
            S += (Ax[i] * Ay[i1] - Ay[i] * Ax[i1]) * fmaxf(t1 - t0, 0.f);
        }
    }
    {
        float dA[4][4];
        #pragma unroll
        for (int j = 0; j < 4; j++) {
            int j1 = (j + 1) & 3;
            float sx = sgnA * (Ax[j1] - Ax[j]);
            float sy = sgnA * (Ay[j1] - Ay[j]);
            float kj = sx * Ay[j] - sy * Ax[j];
            #pragma unroll
            for (int i = 0; i < 4; i++)
                dA[j][i] = sx * By[i] - sy * Bx[i] - kj;
        }
        #pragma unroll
        for (int i = 0; i < 4; i++) {
            int i1 = (i + 1) & 3;
            float t0 = 0.f, t1 = 1.f;
            #pragma unroll
            for (int j = 0; j < 4; j++) {
                float d0 = dA[j][i], d1 = dA[j][i1];
                float den = d1 - d0;
                float t = __fdividef(-d0, den);
                float lo = (den > 0.f) ? t : ((den == 0.f && d0 < 0.f) ? 2.f : 0.f);
                float hi = (den < 0.f) ? t : 1.f;
                t0 = fmaxf(t0, lo);
                t1 = fminf(t1, hi);
            }
            S += (Bx[i] * By[i1] - By[i] * Bx[i1]) * fmaxf(t1 - t0, 0.f);
        }
    }
    float inter = 0.5f * fabsf(S);
    float areaA = fabsf(sa), areaB = fabsf(sb);
    float uni = areaA + areaB - inter;
    float iou = (uni > 1e-7f) ? __fdividef(inter, uni) : 0.f;

    // ---------------- DIoU-style bev loss ----------------
    {
        float ddx = P[0] - T[0], ddy = P[1] - T[1];
        float d2 = fmaf(ddx, ddx, ddy * ddy);
        float mnx = Ax[0], mxx = Ax[0], mny = Ay[0], mxy = Ay[0];
        #pragma unroll
        for (int i = 1; i < 4; i++) {
            mnx = fminf(mnx, Ax[i]); mxx = fmaxf(mxx, Ax[i]);
            mny = fminf(mny, Ay[i]); mxy = fmaxf(mxy, Ay[i]);
        }
        #pragma unroll
        for (int i = 0; i < 4; i++) {
            mnx = fminf(mnx, Bx[i]); mxx = fmaxf(mxx, Bx[i]);
            mny = fminf(mny, By[i]); mxy = fmaxf(mxy, By[i]);
        }
        float exd = mxx - mnx, eyd = mxy - mny;
        float c2 = fmaxf(fmaf(exd, exd, eyd * eyd), 1e-7f);

        // atan(rp) - atan(rt) = atan((rp-rt)/(1+rp*rt))  (rp,rt >= 0 here)
        float rp = __fdividef(P[4], fmaxf(P[3], 1e-7f));
        float rt = __fdividef(T[4], fmaxf(T[3], 1e-7f));
        float dv = atanf(__fdividef(rp - rt, fmaf(rp, rt, 1.f)));
        float v = 0.4052847345693511f * dv * dv;
        float alpha_c = __fdividef(v, 1.0f - iou + v + 1e-7f);
        float lbev = 1.0f - iou + __fdividef(d2, c2) + alpha_c * v;
        o[1] = lbev * pos;
    }

    // ---------------- smooth-L1 z / h / vel + BCE ----------------
    o[2] = sl1f(P[2], T[2]) * pos;
    o[3] = sl1f(P[5], T[5]) * pos;
    o[4] = (sl1f(P[7], T[7]) + sl1f(P[8], T[8])) * pos;
    float bce = fmaxf(xiou, 0.f) - xiou * yiou + __logf(1.0f + __expf(-fabsf(xiou)));
    o[5] = bce * pos;
    o[6] = pos;
}

__global__ __launch_bounds__(256) void bev_loss_main(
    const float* __restrict__ cls_pred, const float* __restrict__ reg_pred,
    const float* __restrict__ iou_pred, const int* __restrict__ cls_tg,
    const float* __restrict__ reg_tg, const float* __restrict__ reg_w,
    const float* __restrict__ iou_tg, double* __restrict__ part)
{
    int t  = blockIdx.x * blockDim.x + threadIdx.x;   // 0 .. 262143
    int n0 = t << 1;                                  // even pixel index
    int b  = n0 >> 16;
    int hw = n0 & 65535;

    // ---------------- vectorized loads (2 pixels), issued together ----------
    float2 lg2[C_];
    {
        const float* cp = cls_pred + (size_t)b * C_ * HW_ + hw;
        #pragma unroll
        for (int c = 0; c < C_; c++)
            lg2[c] = *reinterpret_cast<const float2*>(cp + (size_t)c * HW_);
    }
    float2 P2[9], T2[9];
    {
        const float* rp = reg_pred + (size_t)b * 9 * HW_ + hw;
        const float* rt = reg_tg  + (size_t)b * 9 * HW_ + hw;
        #pragma unroll
        for (int k = 0; k < 9; k++) {
            P2[k] = *reinterpret_cast<const float2*>(rp + (size_t)k * HW_);
            T2[k] = *reinterpret_cast<const float2*>(rt + (size_t)k * HW_);
        }
    }
    int2   ct2 = *reinterpret_cast<const int2*>(cls_tg + n0);
    float2 w2  = *reinterpret_cast<const float2*>(reg_w + n0);
    float2 x2  = *reinterpret_cast<const float2*>(iou_pred + n0);
    float2 y2  = *reinterpret_cast<const float2*>(iou_tg + n0);

    // Pin all loaded values into VGPRs here: forces the loads to issue
    // up-front (latency overlapped) and defeats the load-sinking schedule
    // that produced the VGPR=48 / VALUBusy=8.6% pathology in R5.
    #pragma unroll
    for (int c = 0; c < C_; c++) { pinf(lg2[c].x); pinf(lg2[c].y); }
    #pragma unroll
    for (int k = 0; k < 9; k++) { pinf(P2[k].x); pinf(P2[k].y); pinf(T2[k].x); pinf(T2[k].y); }
    pini(ct2.x); pini(ct2.y);
    pinf(w2.x);  pinf(w2.y);
    pinf(x2.x);  pinf(x2.y);
    pinf(y2.x);  pinf(y2.y);

    // ---------------- two independent pixel pipelines ----------------
    float o0[7], o1[7];
    {
        float lg[C_], P[9], T[9];
        #pragma unroll
        for (int c = 0; c < C_; c++) lg[c] = lg2[c].x;
        #pragma unroll
        for (int k = 0; k < 9; k++) { P[k] = P2[k].x; T[k] = T2[k].x; }
        pixel_loss(lg, ct2.x, P, T, w2.x, x2.x, y2.x, o0);
    }
    {
        float lg[C_], P[9], T[9];
        #pragma unroll
        for (int c = 0; c < C_; c++) lg[c] = lg2[c].y;
        #pragma unroll
        for (int k = 0; k < 9; k++) { P[k] = P2[k].y; T[k] = T2[k].y; }
        pixel_loss(lg, ct2.y, P, T, w2.y, x2.y, y2.y, o1);
    }

    // ---------------- block reduction ----------------
    __shared__ double red[7][4];
    int lane = threadIdx.x & 63;
    int wv   = threadIdx.x >> 6;
    #pragma unroll
    for (int k = 0; k < 7; k++) {
        double s = (double)o0[k] + (double)o1[k];
        for (int off = 32; off > 0; off >>= 1) s += __shfl_down(s, off, 64);
        if (lane == 0) red[k][wv] = s;
    }
    __syncthreads();
    if (threadIdx.x == 0) {
        #pragma unroll
        for (int k = 0; k < 7; k++)
            part[(size_t)k * NB_ + blockIdx.x] = red[k][0] + red[k][1] + red[k][2] + red[k][3];
    }
}

__global__ __launch_bounds__(1024) void bev_loss_fin(
    const double* __restrict__ part, float* __restrict__ out)
{
    int t = threadIdx.x;  // 0..1023, one per main-block partial
    double v[7];
    #pragma unroll
    for (int k = 0; k < 7; k++) v[k] = part[(size_t)k * NB_ + t];

    int lane = t & 63, wv = t >> 6;
    __shared__ double red[7][16];
    #pragma unroll
    for (int k = 0; k < 7; k++) {
        double s = v[k];
        for (int off = 32; off > 0; off >>= 1) s += __shfl_down(s, off, 64);
        if (lane == 0) red[k][wv] = s;
    }
    __syncthreads();
    if (t == 0) {
        double tot[7];
        #pragma unroll
        for (int k = 0; k < 7; k++) {
            double s = 0.0;
            #pragma unroll
            for (int i = 0; i < 16; i++) s += red[k][i];
            tot[k] = s;
        }
        double npos = fmax(tot[6], 1.0);
        #pragma unroll
        for (int k = 0; k < 6; k++) out[k] = (float)(tot[k] / npos);
    }
}

extern "C" void kernel_launch(void* const* d_in, const int* in_sizes, int n_in,
                              void* d_out, int out_size, void* d_ws, size_t ws_size,
                              hipStream_t stream) {
    const float* cls_pred = (const float*)d_in[0];
    const float* reg_pred = (const float*)d_in[1];
    const float* iou_pred = (const float*)d_in[2];
    const int*   cls_tg   = (const int*)d_in[3];
    const float* reg_tg   = (const float*)d_in[4];
    const float* reg_w    = (const float*)d_in[5];
    const float* iou_tg   = (const float*)d_in[6];
    float* out = (float*)d_out;
    double* part = (double*)d_ws;   // 7 * 1024 doubles

    bev_loss_main<<<NB_, 256, 0, stream>>>(cls_pred, reg_pred, iou_pred, cls_tg,
                                           reg_tg, reg_w, iou_tg, part);
    bev_loss_fin<<<1, 1024, 0, stream>>>(part, out);
}